// Round 4
// baseline (74.991 us; speedup 1.0000x reference)
//
#include <hip/hip_runtime.h>

// NeRFDecoderHead: ray-marched occupancy render. ALL I/O float32.
//   inputs: rays_o (R,3), rays_d (R,3), voxel (1,200,200,16), rgb_recon (3,200,200,16)
//   output: depth (R) ++ rgb_marched (R,3), flat.
//
// R3 -> R4: the march kernel is gather-transaction-bound (64 divergent lanes
// x 32 scalar gathers/sample). Repack {dens,r,g,b} into an AoS float4 grid in
// d_ws (one aligned dwordx4 gather per trilinear corner -> 8 gathers/sample,
// 4x fewer L1 transactions). block=64 for even CU load balance.

namespace {
constexpr int DX = 200, DY = 200, DZ = 16;
constexpr int GRID_N = DX * DY * DZ;   // 640000
constexpr int NS = 287;
constexpr float ZSTEP = 0.2f;          // stepsize(0.5) * voxel_size(0.4)
} // namespace

extern "C" __global__ void __launch_bounds__(256)
nerf_repack_kernel(const float* __restrict__ vox,
                   const float* __restrict__ rgbg,
                   float4* __restrict__ packed)
{
    const int i = blockIdx.x * blockDim.x + threadIdx.x;
    if (i >= GRID_N) return;
    packed[i] = make_float4(vox[i], rgbg[i], rgbg[GRID_N + i], rgbg[2 * GRID_N + i]);
}

extern "C" __global__ void __launch_bounds__(64)
nerf_march_kernel(const float* __restrict__ ro,
                  const float* __restrict__ rd,
                  const float4* __restrict__ g4,
                  float* __restrict__ out, int R)
{
    const int r = blockIdx.x * blockDim.x + threadIdx.x;
    if (r >= R) return;

    const float ox = ro[3 * r + 0];
    const float oy = ro[3 * r + 1];
    const float oz = ro[3 * r + 2];
    const float dx = rd[3 * r + 0];
    const float dy = rd[3 * r + 1];
    const float dz = rd[3 * r + 2];

    float c = 0.0f;                 // running (unclamped) cumsum of probs_raw
    float depth = 0.0f;
    float a0 = 0.0f, a1 = 0.0f, a2 = 0.0f;
    const float zlast = ZSTEP * (float)(NS - 1);   // 57.2

    #pragma unroll 1
    for (int n = 0; n < NS; ++n) {
        const float z  = ZSTEP * (float)n;
        const float px = ox + dx * z;
        const float py = oy + dy * z;
        const float pz = oz + dz * z;

        const bool inside = (px >= -40.0f) & (px <= 40.0f) &
                            (py >= -40.0f) & (py <= 40.0f) &
                            (pz >= -1.0f)  & (pz <= 5.4f);
        if (!inside) {
            // bbox convex + origin inside => all later samples outside; only
            // the forced last sample (p_raw = 1) remains, rgb zeroed outside.
            if (c < 1.0f) depth += (1.0f - c) * zlast;
            break;
        }

        // trilinear index/weights (align_corners=true: idx = u*(dim-1))
        float fx = fminf(fmaxf((px + 40.0f) * 2.4875f,  0.0f), 199.0f);
        float fy = fminf(fmaxf((py + 40.0f) * 2.4875f,  0.0f), 199.0f);
        float fz = fminf(fmaxf((pz + 1.0f)  * 2.34375f, 0.0f), 15.0f);
        int ix = min((int)fx, DX - 2);   // fx >= 0 so cast == floor
        int iy = min((int)fy, DY - 2);
        int iz = min((int)fz, DZ - 2);
        const float wx = fx - (float)ix, wy = fy - (float)iy, wz = fz - (float)iz;
        const float ux = 1.0f - wx, uy = 1.0f - wy, uz = 1.0f - wz;

        const float w000 = ux * uy * uz, w001 = ux * uy * wz;
        const float w010 = ux * wy * uz, w011 = ux * wy * wz;
        const float w100 = wx * uy * uz, w101 = wx * uy * wz;
        const float w110 = wx * wy * uz, w111 = wx * wy * wz;

        const int SX = DY * DZ;   // 3200
        const int SY = DZ;        // 16
        const int base = (ix * DY + iy) * DZ + iz;

        // 8 aligned float4 gathers: {dens, r, g, b} per corner
        const float4 q000 = g4[base];
        const float4 q001 = g4[base + 1];
        const float4 q010 = g4[base + SY];
        const float4 q011 = g4[base + SY + 1];
        const float4 q100 = g4[base + SX];
        const float4 q101 = g4[base + SX + 1];
        const float4 q110 = g4[base + SX + SY];
        const float4 q111 = g4[base + SX + SY + 1];

        const float dens =
            q000.x * w000 + q001.x * w001 + q010.x * w010 + q011.x * w011 +
            q100.x * w100 + q101.x * w101 + q110.x * w110 + q111.x * w111;

        const float sig = 1.0f / (1.0f + __expf(-dens));
        const float newc = c + sig;
        const float p = fminf(newc, 1.0f) - fminf(c, 1.0f);

        depth += p * z;
        a0 += p * (q000.y * w000 + q001.y * w001 + q010.y * w010 + q011.y * w011 +
                   q100.y * w100 + q101.y * w101 + q110.y * w110 + q111.y * w111);
        a1 += p * (q000.z * w000 + q001.z * w001 + q010.z * w010 + q011.z * w011 +
                   q100.z * w100 + q101.z * w101 + q110.z * w110 + q111.z * w111);
        a2 += p * (q000.w * w000 + q001.w * w001 + q010.w * w010 + q011.w * w011 +
                   q100.w * w100 + q101.w * w101 + q110.w * w110 + q111.w * w111);

        c = newc;
        if (c >= 1.0f) break;   // saturated: every later probs[n] == 0
    }

    out[r]             = depth;
    out[R + 3 * r]     = a0;
    out[R + 3 * r + 1] = a1;
    out[R + 3 * r + 2] = a2;
}

extern "C" void kernel_launch(void* const* d_in, const int* in_sizes, int n_in,
                              void* d_out, int out_size, void* d_ws, size_t ws_size,
                              hipStream_t stream) {
    const float* ro   = (const float*)d_in[0];
    const float* rd   = (const float*)d_in[1];
    const float* vox  = (const float*)d_in[2];
    const float* rgbg = (const float*)d_in[3];
    float* out = (float*)d_out;
    float4* packed = (float4*)d_ws;   // 640000 * 16 B = 10.24 MB scratch

    const int R = in_sizes[0] / 3;    // 86400

    nerf_repack_kernel<<<(GRID_N + 255) / 256, 256, 0, stream>>>(vox, rgbg, packed);
    nerf_march_kernel<<<(R + 63) / 64, 64, 0, stream>>>(ro, rd, packed, out, R);
}